// Round 2
// baseline (36.598 us; speedup 1.0000x reference)
//
#include <hip/hip_runtime.h>
#include <math.h>

// ---------------------------------------------------------------------------
// N-pair Gaussian mixture log-likelihood, factorized form:
//   arg_ij(x) = g_i(x) + g_j(x) + c_ij,  g_i(x) = -0.5 x'prec_i x + x'rhs_i
//   pdf(x)    = u' E u,  u_i = exp(g_i(x)),  E_ij = exp(c_ij + 64 ln2)  [scaled]
//   out       = mean_n( log pdf_n ) + log z_last   (scale folded into Kconst)
// ---------------------------------------------------------------------------

#define LOG2E_F 1.4426950408889634f
#define LN2_F   0.6931471805599453f
#define LN2PI_F 1.8378770664093453f   // ln(2*pi)

// ws layout (float offsets)
#define WS_COEF 0      // 16 components * 48 floats: 36 quad (log2e-scaled), 8 lin, 4 pad
#define WS_E    768    // 256 floats: scaled pair weights E'
#define WS_K    1024   // 1 float: Kconst = log z_last - 64 ln2
#define WS_PREC 1056   // 16 * 72: prec[64] + rhs[8] per component
#define WS_PART 2304   // per-block partial sums (up to ~2048)

__device__ __forceinline__ float fexp2(float x) {
#if __has_builtin(__builtin_amdgcn_exp2f)
  return __builtin_amdgcn_exp2f(x);
#else
  return exp2f(x);
#endif
}
__device__ __forceinline__ float flog2(float x) {
#if __has_builtin(__builtin_amdgcn_logf)
  return __builtin_amdgcn_logf(x);
#else
  return log2f(x);
#endif
}

// Cholesky: A = C C^T (lower). Only lower triangle of A read. Fully unrolled.
__device__ __forceinline__ void chol8(const float (*A)[8], float (*C)[8]) {
  #pragma unroll
  for (int d = 0; d < 8; ++d) {
    float s = A[d][d];
    #pragma unroll
    for (int m = 0; m < 8; ++m) if (m < d) s -= C[d][m] * C[d][m];
    float cd = sqrtf(s);
    C[d][d] = cd;
    float inv = 1.f / cd;
    #pragma unroll
    for (int e = 0; e < 8; ++e) if (e > d) {
      float t = A[e][d];
      #pragma unroll
      for (int m = 0; m < 8; ++m) if (m < d) t -= C[e][m] * C[d][m];
      C[e][d] = t * inv;
    }
  }
}

// Kernel 1: per-component prec_k = inv(tril(L)tril(L)' + I), rhs_k = prec_k mu_k
__global__ void gm_prec_k(const float* __restrict__ mu, const float* __restrict__ L,
                          float* __restrict__ ws) {
  int k = threadIdx.x;
  if (k >= 16) return;
  float Lt[8][8];
  #pragma unroll
  for (int d = 0; d < 8; ++d)
    #pragma unroll
    for (int e = 0; e < 8; ++e)
      Lt[d][e] = (e <= d) ? L[k * 64 + d * 8 + e] : 0.f;
  float A[8][8];
  #pragma unroll
  for (int d = 0; d < 8; ++d)
    #pragma unroll
    for (int e = 0; e <= d; ++e) {
      float s = (d == e) ? 1.f : 0.f;
      #pragma unroll
      for (int m = 0; m < 8; ++m) s += Lt[d][m] * Lt[e][m];
      A[d][e] = s;
      A[e][d] = s;
    }
  float C[8][8];
  chol8(A, C);
  // Ci = inv(C), lower triangular
  float Ci[8][8];
  #pragma unroll
  for (int d = 0; d < 8; ++d) Ci[d][d] = 1.f / C[d][d];
  #pragma unroll
  for (int e = 0; e < 8; ++e)
    #pragma unroll
    for (int d = 0; d < 8; ++d) if (d > e) {
      float s = 0.f;
      #pragma unroll
      for (int m = 0; m < 8; ++m) if (m >= e && m < d) s += C[d][m] * Ci[m][e];
      Ci[d][e] = -s * Ci[d][d];
    }
  // prec = Ci' Ci
  float Pr[8][8];
  #pragma unroll
  for (int a = 0; a < 8; ++a)
    #pragma unroll
    for (int b = 0; b < 8; ++b) {
      float s = 0.f;
      #pragma unroll
      for (int m = 0; m < 8; ++m) if (m >= a && m >= b) s += Ci[m][a] * Ci[m][b];
      Pr[a][b] = s;
    }
  float* o = ws + WS_PREC + k * 72;
  #pragma unroll
  for (int a = 0; a < 8; ++a)
    #pragma unroll
    for (int b = 0; b < 8; ++b) o[a * 8 + b] = Pr[a][b];
  #pragma unroll
  for (int d = 0; d < 8; ++d) {
    float s = 0.f;
    #pragma unroll
    for (int e = 0; e < 8; ++e) s += Pr[d][e] * mu[k * 8 + e];
    o[64 + d] = s;
  }
}

// Kernel 2: per-pair constants E'_ij and per-component main-loop coefficients
__global__ void gm_pair_k(const float* __restrict__ wts, float* __restrict__ ws) {
  int p = threadIdx.x;
  if (p >= 256) return;
  int i = p >> 4, j = p & 15;
  const float* pi = ws + WS_PREC + i * 72;
  const float* pj = ws + WS_PREC + j * 72;
  float P[8][8], rp[8];
  #pragma unroll
  for (int d = 0; d < 8; ++d) {
    #pragma unroll
    for (int e = 0; e < 8; ++e) P[d][e] = pi[d * 8 + e] + pj[d * 8 + e];
    rp[d] = pi[64 + d] + pj[64 + d];
  }
  float U[8][8];
  chol8(P, U);
  float logdet = 0.f;
  #pragma unroll
  for (int d = 0; d < 8; ++d) logdet += logf(U[d][d]);
  logdet *= 2.f;
  // solve P y = rp via U (forward, then back)
  float zf[8];
  #pragma unroll
  for (int d = 0; d < 8; ++d) {
    float s = rp[d];
    #pragma unroll
    for (int m = 0; m < 8; ++m) if (m < d) s -= U[d][m] * zf[m];
    zf[d] = s / U[d][d];
  }
  float y[8];
  #pragma unroll
  for (int dd = 7; dd >= 0; --dd) {
    float s = zf[dd];
    #pragma unroll
    for (int m = 0; m < 8; ++m) if (m > dd) s -= U[m][dd] * y[m];
    y[dd] = s / U[dd][dd];
  }
  float muPmu = 0.f;
  #pragma unroll
  for (int d = 0; d < 8; ++d) muPmu += rp[d] * y[d];
  // c'_ij = -0.5 mu'Pmu + 0.5 log det P - 32 ln(2pi) + ln w_i + ln w_j + 64 ln2
  float c = -0.5f * muPmu + 0.5f * logdet - 32.f * LN2PI_F
          + logf(wts[i]) + logf(wts[j]) + 64.f * LN2_F;
  ws[WS_E + p] = expf(c);
  if (i == j) {
    // per-component coefficients, pre-scaled by log2(e)
    float* c0 = ws + WS_COEF + i * 48;
    int q = 0;
    #pragma unroll
    for (int d = 0; d < 8; ++d)
      #pragma unroll
      for (int e = d; e < 8; ++e) {
        float v = (d == e) ? -0.5f * pi[d * 8 + e] : -pi[d * 8 + e];
        c0[q++] = v * LOG2E_F;
      }
    #pragma unroll
    for (int d = 0; d < 8; ++d) c0[36 + d] = pi[64 + d] * LOG2E_F;
    c0[44] = 0.f; c0[45] = 0.f; c0[46] = 0.f; c0[47] = 0.f;
  }
  if (p == 255) ws[WS_K] = 0.5f * logdet - 32.f * LN2PI_F - 64.f * LN2_F;
}

// Kernel 3: main N-loop. One x per thread; coefficient reads are wave-uniform.
__global__ __launch_bounds__(256) void gm_main(const float* __restrict__ X,
                                               const float* __restrict__ ws,
                                               float* __restrict__ partials,
                                               int N) {
  int gid = blockIdx.x * 256 + threadIdx.x;
  const float* __restrict__ coef = ws + WS_COEF;
  const float* __restrict__ Em = ws + WS_E;
  float lsum = 0.f;
  if (gid < N) {
    const float4* Xv = reinterpret_cast<const float4*>(X) + (size_t)gid * 2;
    float4 xa = Xv[0];
    float4 xb = Xv[1];
    float xv[8] = {xa.x, xa.y, xa.z, xa.w, xb.x, xb.y, xb.z, xb.w};
    float prods[36];
    {
      int q = 0;
      #pragma unroll
      for (int d = 0; d < 8; ++d)
        #pragma unroll
        for (int e = d; e < 8; ++e) prods[q++] = xv[d] * xv[e];
    }
    float u[16];
    #pragma unroll 4
    for (int i = 0; i < 16; ++i) {
      const float* c = coef + i * 48;
      float a0 = 0.f, a1 = 0.f, a2 = 0.f, a3 = 0.f;
      #pragma unroll
      for (int q = 0; q < 36; q += 4) {
        a0 = fmaf(c[q + 0], prods[q + 0], a0);
        a1 = fmaf(c[q + 1], prods[q + 1], a1);
        a2 = fmaf(c[q + 2], prods[q + 2], a2);
        a3 = fmaf(c[q + 3], prods[q + 3], a3);
      }
      a0 = fmaf(c[36], xv[0], a0); a1 = fmaf(c[37], xv[1], a1);
      a2 = fmaf(c[38], xv[2], a2); a3 = fmaf(c[39], xv[3], a3);
      a0 = fmaf(c[40], xv[4], a0); a1 = fmaf(c[41], xv[5], a1);
      a2 = fmaf(c[42], xv[6], a2); a3 = fmaf(c[43], xv[7], a3);
      u[i] = fexp2((a0 + a1) + (a2 + a3));  // u_i = e^{g_i}, log2e pre-folded
    }
    float pdf = 0.f;
    #pragma unroll 4
    for (int i = 0; i < 16; ++i) {
      const float* e = Em + i * 16;
      float t0 = 0.f, t1 = 0.f;
      #pragma unroll
      for (int j = 0; j < 16; j += 2) {
        t0 = fmaf(e[j + 0], u[j + 0], t0);
        t1 = fmaf(e[j + 1], u[j + 1], t1);
      }
      pdf = fmaf(u[i], t0 + t1, pdf);
    }
    lsum = flog2(pdf);
  }
  // deterministic block reduction of sum(log2 pdf)
  #pragma unroll
  for (int off = 32; off > 0; off >>= 1) lsum += __shfl_down(lsum, off, 64);
  __shared__ float wsum[4];
  int lane = threadIdx.x & 63, wid = threadIdx.x >> 6;
  if (lane == 0) wsum[wid] = lsum;
  __syncthreads();
  if (threadIdx.x == 0)
    partials[blockIdx.x] = (wsum[0] + wsum[1]) + (wsum[2] + wsum[3]);
}

// Kernel 4: deterministic final reduction
__global__ void gm_final(const float* __restrict__ ws, float* __restrict__ out,
                         int nb, float invN) {
  const float* partials = ws + WS_PART;
  float s = 0.f;
  for (int t = threadIdx.x; t < nb; t += 256) s += partials[t];
  #pragma unroll
  for (int off = 32; off > 0; off >>= 1) s += __shfl_down(s, off, 64);
  __shared__ float wsum[4];
  int lane = threadIdx.x & 63, wid = threadIdx.x >> 6;
  if (lane == 0) wsum[wid] = s;
  __syncthreads();
  if (threadIdx.x == 0) {
    float tot = (wsum[0] + wsum[1]) + (wsum[2] + wsum[3]);
    // mean(ln pdf_true) + ln z_last = ln2 * mean(log2 pdf_scaled) + Kconst
    out[0] = tot * LN2_F * invN + ws[WS_K];
  }
}

extern "C" void kernel_launch(void* const* d_in, const int* in_sizes, int n_in,
                              void* d_out, int out_size, void* d_ws, size_t ws_size,
                              hipStream_t stream) {
  const float* X = (const float*)d_in[0];
  const float* mu = (const float*)d_in[1];
  const float* L = (const float*)d_in[2];
  const float* wts = (const float*)d_in[3];
  // d_in[4] ("it") is unused by the reference math.
  float* ws = (float*)d_ws;
  float* out = (float*)d_out;
  int N = in_sizes[0] / 8;
  int nb = (N + 255) / 256;
  gm_prec_k<<<1, 64, 0, stream>>>(mu, L, ws);
  gm_pair_k<<<1, 256, 0, stream>>>(wts, ws);
  gm_main<<<nb, 256, 0, stream>>>(X, ws, ws + WS_PART, N);
  gm_final<<<1, 256, 0, stream>>>(ws, out, nb, 1.0f / (float)N);
}